// Round 2
// baseline (138.482 us; speedup 1.0000x reference)
//
#include <hip/hip_runtime.h>
#include <hip/hip_bf16.h>

typedef __attribute__((ext_vector_type(8))) short bf16x8;
typedef __attribute__((ext_vector_type(4))) float f32x4;
typedef __attribute__((ext_vector_type(4))) unsigned int u32x4;
typedef __attribute__((ext_vector_type(2))) unsigned int u32x2;

__device__ __forceinline__ float b2f(unsigned short u) {
  unsigned int x = ((unsigned int)u) << 16;
  float f;
  __builtin_memcpy(&f, &x, 4);
  return f;
}
__device__ __forceinline__ unsigned short f2b(float f) {
  __hip_bfloat16 h = __float2bfloat16(f);
  unsigned short u;
  __builtin_memcpy(&u, &h, 2);
  return u;
}

__device__ __forceinline__ float ldE(const float* p) { return *p; }
__device__ __forceinline__ float ldE(const unsigned short* p) { return b2f(*p); }
__device__ __forceinline__ void stC(float* p, float v) { *p = v; }
__device__ __forceinline__ void stC(unsigned short* p, float v) { *p = f2b(v); }

// ---------------------------------------------------------------------------
// f32 [batch][R][C]  ->  bf16 [batch][C][R]   (64x64 tiles)
// grid: (C/64, R/64, batch), block 256.
// ---------------------------------------------------------------------------
__global__ __launch_bounds__(256) void conv_transpose64(
    const float* __restrict__ src, unsigned short* __restrict__ dst,
    int R, int C) {
  __shared__ unsigned short tile[64][68];  // row stride 136 B (8B-aligned)
  const int b = blockIdx.z;
  const float* s = src + (size_t)b * R * C;
  unsigned short* d = dst + (size_t)b * R * C;
  const int r0 = blockIdx.y * 64, c0 = blockIdx.x * 64;
  const int t = threadIdx.x;
#pragma unroll
  for (int p = 0; p < 4; ++p) {
    const int id = t + 256 * p;          // 0..1023
    const int r = id >> 4, c4 = (id & 15) * 4;
    f32x4 v = *(const f32x4*)(s + (size_t)(r0 + r) * C + (c0 + c4));
#pragma unroll
    for (int j = 0; j < 4; ++j) tile[r][c4 + j] = f2b(v[j]);
  }
  __syncthreads();
#pragma unroll
  for (int p = 0; p < 2; ++p) {
    const int id = t + 256 * p;          // 0..511
    const int oc = id >> 3, cr8 = (id & 7) * 8;  // dst row = src col
    u32x4 v;
    unsigned short* pv = (unsigned short*)&v;
#pragma unroll
    for (int j = 0; j < 8; ++j) pv[j] = tile[cr8 + j][oc];
    *(u32x4*)(d + (size_t)(c0 + oc) * R + (r0 + cr8)) = v;
  }
}

// ---------------------------------------------------------------------------
// straight f32 -> bf16 convert (adj). n multiple of 1024.
// ---------------------------------------------------------------------------
__global__ __launch_bounds__(256) void conv_bf16(const float* __restrict__ src,
                                                 unsigned short* __restrict__ dst,
                                                 int n) {
  const int i = (blockIdx.x * 256 + threadIdx.x) * 4;
  if (i >= n) return;
  f32x4 v = *(const f32x4*)(src + i);
  unsigned short o[4];
#pragma unroll
  for (int j = 0; j < 4; ++j) o[j] = f2b(v[j]);
  u32x2 pk;
  __builtin_memcpy(&pk, o, 8);
  *(u32x2*)(dst + i) = pk;
}

// ---------------------------------------------------------------------------
// C[b] = CT( c0 * (A[b] · BT[b]^T) + c1 * E[b] ),  1024x1024 per batch.
// A  [M,K] bf16 row-major (strideA==0 -> shared across batch)
// BT [N,K] bf16 row-major (B pre-transposed; strideB==0 -> shared)
// E  [M,N] ET (f32 or bf16); C [M,N] CT (f32 or bf16)
// 128x128 tile, BK=64, 4 waves (64x64 each), mfma_f32_16x16x32_bf16.
// global_load_lds 16B, linear LDS dest, XOR chunk swizzle on global source
// and on the ds_read side (rule #21).
// ---------------------------------------------------------------------------
template <typename ET, typename CT>
__global__ __launch_bounds__(256) void gemm_bt_fused(
    const unsigned short* __restrict__ A, size_t strideA,
    const unsigned short* __restrict__ BT, size_t strideB,
    const ET* __restrict__ E, size_t strideE,
    CT* __restrict__ C, size_t strideC, float c0, float c1) {
  constexpr int K = 1024;
  __shared__ unsigned short Abuf[128 * 64];
  __shared__ unsigned short Bbuf[128 * 64];
  const int b = blockIdx.z;
  const unsigned short* Ab = A + (size_t)b * strideA;
  const unsigned short* Bb = BT + (size_t)b * strideB;
  const int m0 = blockIdx.y * 128, n0 = blockIdx.x * 128;
  const int t = threadIdx.x, lane = t & 63, w = t >> 6;
  const int wm = (w >> 1) * 64, wn = (w & 1) * 64;

  f32x4 acc[4][4];
#pragma unroll
  for (int i = 0; i < 4; ++i)
#pragma unroll
    for (int j = 0; j < 4; ++j) acc[i][j] = (f32x4){0.f, 0.f, 0.f, 0.f};

  for (int k0 = 0; k0 < K; k0 += 64) {
    __syncthreads();
#pragma unroll
    for (int i = 0; i < 4; ++i) {
      const int reg = w * 4 + i;                        // 0..15
      const int row = reg * 8 + (lane >> 3);            // 0..127
      const int col8 = (((lane & 7) ^ (row & 7)) << 3); // swizzled src chunk
      const unsigned short* ga = Ab + (size_t)(m0 + row) * K + (k0 + col8);
      const unsigned short* gb = Bb + (size_t)(n0 + row) * K + (k0 + col8);
      __builtin_amdgcn_global_load_lds(
          (const __attribute__((address_space(1))) unsigned int*)ga,
          (__attribute__((address_space(3))) unsigned int*)(Abuf + reg * 512),
          16, 0, 0);
      __builtin_amdgcn_global_load_lds(
          (const __attribute__((address_space(1))) unsigned int*)gb,
          (__attribute__((address_space(3))) unsigned int*)(Bbuf + reg * 512),
          16, 0, 0);
    }
    asm volatile("s_waitcnt vmcnt(0)" ::: "memory");
    __syncthreads();

#pragma unroll
    for (int kk = 0; kk < 2; ++kk) {
      bf16x8 af[4], bfr[4];
#pragma unroll
      for (int mi = 0; mi < 4; ++mi) {
        const int row = wm + mi * 16 + (lane & 15);
        const int ch = ((kk * 4 + (lane >> 4)) ^ (row & 7)) << 3;
        af[mi] = *(const bf16x8*)(Abuf + row * 64 + ch);
      }
#pragma unroll
      for (int nj = 0; nj < 4; ++nj) {
        const int row = wn + nj * 16 + (lane & 15);
        const int ch = ((kk * 4 + (lane >> 4)) ^ (row & 7)) << 3;
        bfr[nj] = *(const bf16x8*)(Bbuf + row * 64 + ch);
      }
#pragma unroll
      for (int mi = 0; mi < 4; ++mi)
#pragma unroll
        for (int nj = 0; nj < 4; ++nj)
          acc[mi][nj] = __builtin_amdgcn_mfma_f32_16x16x32_bf16(
              af[mi], bfr[nj], acc[mi][nj], 0, 0, 0);
    }
  }

  const ET* Eb = E + (size_t)b * strideE;
  CT* Cb = C + (size_t)b * strideC;
#pragma unroll
  for (int mi = 0; mi < 4; ++mi) {
#pragma unroll
    for (int r = 0; r < 4; ++r) {
      const int row = m0 + wm + mi * 16 + (lane >> 4) * 4 + r;
#pragma unroll
      for (int nj = 0; nj < 4; ++nj) {
        const int col = n0 + wn + nj * 16 + (lane & 15);
        const float v =
            c0 * acc[mi][nj][r] + c1 * ldE(Eb + (size_t)row * 1024 + col);
        stC(Cb + (size_t)row * 1024 + col, v);
      }
    }
  }
}

// ---------------------------------------------------------------------------
// out = theta*(support·W) + (1-theta)*support
// support = 0.9*(adj·X_b) + 0.1*h0 ;  theta = log(1.5) (static: lamda=.5, l=1)
// ---------------------------------------------------------------------------
extern "C" void kernel_launch(void* const* d_in, const int* in_sizes, int n_in,
                              void* d_out, int out_size, void* d_ws,
                              size_t ws_size, hipStream_t stream) {
  const float* X = (const float*)d_in[0];    // [16,1024,1024] f32
  const float* adj = (const float*)d_in[1];  // [1024,1024] f32
  const float* h0 = (const float*)d_in[2];   // [16,1024,1024] f32
  const float* W = (const float*)d_in[3];    // [1024,1024] f32
  float* out = (float*)d_out;                // [16,1024,1024] f32

  const size_t NF = 1024ull * 1024ull;
  unsigned short* XT = (unsigned short*)d_ws;  // 16*NF bf16 (32 MB)
  unsigned short* WT = XT + 16 * NF;           // NF bf16 (2 MB)
  unsigned short* AJ = WT + NF;                // NF bf16 (2 MB)
  unsigned short* S = AJ + NF;                 // 16*NF bf16 (32 MB)

  const float theta = 0.405465108f;  // log(1.5)
  const float alpha = 0.1f;

  // XT[b][f][n] = bf16(X[b][n][f]);  WT[o][f] = bf16(W[f][o]);  AJ = bf16(adj)
  conv_transpose64<<<dim3(16, 16, 16), 256, 0, stream>>>(X, XT, 1024, 1024);
  conv_transpose64<<<dim3(16, 16, 1), 256, 0, stream>>>(W, WT, 1024, 1024);
  conv_bf16<<<dim3(1024), 256, 0, stream>>>(adj, AJ, 1024 * 1024);

  // S = bf16( 0.9*(adj · X_b) + 0.1*h0 )
  gemm_bt_fused<float, unsigned short>
      <<<dim3(8, 8, 16), 256, 0, stream>>>(AJ, 0, XT, NF, h0, NF, S, NF,
                                           1.0f - alpha, alpha);
  // out = f32( theta*(S · W) + (1-theta)*S )
  gemm_bt_fused<unsigned short, float>
      <<<dim3(8, 8, 16), 256, 0, stream>>>(S, NF, WT, 0, S, NF, out, NF,
                                           theta, 1.0f - theta);
}

// Round 3
// 113.386 us; speedup vs baseline: 1.2213x; 1.2213x over previous
//
#include <hip/hip_runtime.h>
#include <hip/hip_bf16.h>

typedef __attribute__((ext_vector_type(8))) short bf16x8;
typedef __attribute__((ext_vector_type(4))) float f32x4;
typedef __attribute__((ext_vector_type(4))) unsigned int u32x4;
typedef __attribute__((ext_vector_type(2))) unsigned int u32x2;

__device__ __forceinline__ float b2f(unsigned short u) {
  unsigned int x = ((unsigned int)u) << 16;
  float f;
  __builtin_memcpy(&f, &x, 4);
  return f;
}
__device__ __forceinline__ unsigned short f2b(float f) {
  __hip_bfloat16 h = __float2bfloat16(f);
  unsigned short u;
  __builtin_memcpy(&u, &h, 2);
  return u;
}
__device__ __forceinline__ float ldE(const float* p) { return *p; }
__device__ __forceinline__ float ldE(const unsigned short* p) { return b2f(*p); }
__device__ __forceinline__ void stC(float* p, float v) { *p = v; }
__device__ __forceinline__ void stC(unsigned short* p, float v) { *p = f2b(v); }

// ---------------------------------------------------------------------------
// f32 [batch][R][C] -> bf16 [batch][C][R]  (64x64 tiles)
// ---------------------------------------------------------------------------
__global__ __launch_bounds__(256) void conv_transpose64(
    const float* __restrict__ src, unsigned short* __restrict__ dst,
    int R, int C) {
  __shared__ unsigned short tile[64][68];
  const int b = blockIdx.z;
  const float* s = src + (size_t)b * R * C;
  unsigned short* d = dst + (size_t)b * R * C;
  const int r0 = blockIdx.y * 64, c0 = blockIdx.x * 64;
  const int t = threadIdx.x;
#pragma unroll
  for (int p = 0; p < 4; ++p) {
    const int id = t + 256 * p;
    const int r = id >> 4, c4 = (id & 15) * 4;
    f32x4 v = *(const f32x4*)(s + (size_t)(r0 + r) * C + (c0 + c4));
#pragma unroll
    for (int j = 0; j < 4; ++j) tile[r][c4 + j] = f2b(v[j]);
  }
  __syncthreads();
#pragma unroll
  for (int p = 0; p < 2; ++p) {
    const int id = t + 256 * p;
    const int oc = id >> 3, cr8 = (id & 7) * 8;
    u32x4 v;
    unsigned short* pv = (unsigned short*)&v;
#pragma unroll
    for (int j = 0; j < 8; ++j) pv[j] = tile[cr8 + j][oc];
    *(u32x4*)(d + (size_t)(c0 + oc) * R + (r0 + cr8)) = v;
  }
}

// ---------------------------------------------------------------------------
// W' transpose: dst[o][f] = bf16( scale*W[f][o] + diag*(o==f) )   (1024x1024)
// ---------------------------------------------------------------------------
__global__ __launch_bounds__(256) void conv_transpose_wprime(
    const float* __restrict__ src, unsigned short* __restrict__ dst,
    float scale, float diag) {
  __shared__ float tile[64][65];
  const int r0 = blockIdx.y * 64, c0 = blockIdx.x * 64;
  const int t = threadIdx.x;
#pragma unroll
  for (int p = 0; p < 4; ++p) {
    const int id = t + 256 * p;
    const int r = id >> 4, c4 = (id & 15) * 4;
    f32x4 v = *(const f32x4*)(src + (size_t)(r0 + r) * 1024 + (c0 + c4));
#pragma unroll
    for (int j = 0; j < 4; ++j) tile[r][c4 + j] = v[j];
  }
  __syncthreads();
#pragma unroll
  for (int p = 0; p < 2; ++p) {
    const int id = t + 256 * p;
    const int oc = id >> 3, cr8 = (id & 7) * 8;  // dst row o = c0+oc
    u32x4 v;
    unsigned short* pv = (unsigned short*)&v;
#pragma unroll
    for (int j = 0; j < 8; ++j) {
      const int o = c0 + oc, f = r0 + cr8 + j;
      float val = scale * tile[cr8 + j][oc] + (o == f ? diag : 0.f);
      pv[j] = f2b(val);
    }
    *(u32x4*)(dst + (size_t)(c0 + oc) * 1024 + (r0 + cr8)) = v;
  }
}

// ---------------------------------------------------------------------------
// straight f32 -> bf16 convert (adj).
// ---------------------------------------------------------------------------
__global__ __launch_bounds__(256) void conv_bf16(const float* __restrict__ src,
                                                 unsigned short* __restrict__ dst,
                                                 int n) {
  const int i = (blockIdx.x * 256 + threadIdx.x) * 4;
  if (i >= n) return;
  f32x4 v = *(const f32x4*)(src + i);
  unsigned short o[4];
#pragma unroll
  for (int j = 0; j < 4; ++j) o[j] = f2b(v[j]);
  u32x2 pk;
  __builtin_memcpy(&pk, o, 8);
  *(u32x2*)(dst + i) = pk;
}

// ---------------------------------------------------------------------------
// 256x256-tile 8-phase GEMM:  C[b] = CT( c0*(A[b]·BT[b]^T) + c1*E[b] )
// M=N=K=1024. 512 threads = 8 waves (2M x 4N), per-wave 128x64 output.
// LDS: 2 dbuf x (A 256x64 + B 256x64) bf16 = 128 KB, XOR chunk swizzle.
// Per K-tile: 4 phases {dsread subtile | stage half-tile | bar | lgkm0 |
// setprio 16xMFMA | bar}; counted vmcnt(4) once per K-tile (never 0).
// ---------------------------------------------------------------------------
template <typename ET, typename CT, bool HASE>
__global__ __launch_bounds__(512, 2) void gemm256(
    const unsigned short* __restrict__ A, size_t strideA,
    const unsigned short* __restrict__ BT, size_t strideB,
    const ET* __restrict__ E, size_t strideE,
    CT* __restrict__ C, size_t strideC, float c0, float c1) {
  constexpr int K = 1024;
  constexpr int NT = 16;  // K/64
  __shared__ unsigned short lds[4][16384];  // [buf*2+op][256*64]
  const int b = blockIdx.z;
  const unsigned short* Ab = A + (size_t)b * strideA;
  const unsigned short* Bb = BT + (size_t)b * strideB;
  const int m0 = blockIdx.y * 256, n0 = blockIdx.x * 256;
  const int t = threadIdx.x, lane = t & 63, wv = t >> 6;
  const int wm = (wv >> 2) * 128, wn = (wv & 3) * 64;

  f32x4 acc[8][4];
#pragma unroll
  for (int i = 0; i < 8; ++i)
#pragma unroll
    for (int j = 0; j < 4; ++j) acc[i][j] = (f32x4){0.f, 0.f, 0.f, 0.f};

  bf16x8 areg[4][2], b0r[2][2], b1r[2][2];

  // stage one half-tile (128 rows x 64 cols): 2 global_load_lds per thread
  auto STAGE = [&](int buf, int op, int half, const unsigned short* gbase,
                   int rowbase, int k0) {
#pragma unroll
    for (int l = 0; l < 2; ++l) {
      const int id = l * 512 + t;
      const int rl = id >> 3, c = id & 7;
      const int gc = (c ^ (rl & 7)) << 3;  // pre-swizzled global chunk
      const unsigned short* g =
          gbase + (size_t)(rowbase + half * 128 + rl) * K + k0 + gc;
      unsigned short* dst =
          &lds[buf * 2 + op][half * 8192 + (l * 512 + wv * 64) * 8];
      __builtin_amdgcn_global_load_lds(
          (const __attribute__((address_space(1))) unsigned int*)g,
          (__attribute__((address_space(3))) unsigned int*)dst, 16, 0, 0);
    }
  };

#define LOAD_A(MH)                                                     \
  {                                                                    \
    const unsigned short* Ard = lds[rd * 2 + 0];                       \
    _Pragma("unroll") for (int mi = 0; mi < 4; ++mi)                   \
        _Pragma("unroll") for (int kk = 0; kk < 2; ++kk) {             \
      const int row = wm + (MH)*64 + mi * 16 + (lane & 15);            \
      const int ch = ((kk * 4 + (lane >> 4)) ^ (row & 7)) << 3;        \
      areg[mi][kk] = *(const bf16x8*)(Ard + row * 64 + ch);            \
    }                                                                  \
  }
#define LOAD_B(NH, BR)                                                 \
  {                                                                    \
    const unsigned short* Brd = lds[rd * 2 + 1];                       \
    _Pragma("unroll") for (int nj = 0; nj < 2; ++nj)                   \
        _Pragma("unroll") for (int kk = 0; kk < 2; ++kk) {             \
      const int row = wn + (NH)*32 + nj * 16 + (lane & 15);            \
      const int ch = ((kk * 4 + (lane >> 4)) ^ (row & 7)) << 3;        \
      BR[nj][kk] = *(const bf16x8*)(Brd + row * 64 + ch);              \
    }                                                                  \
  }
#define MFMA_Q(MH, NH, BR)                                             \
  do {                                                                 \
    __builtin_amdgcn_s_setprio(1);                                     \
    _Pragma("unroll") for (int mi = 0; mi < 4; ++mi)                   \
        _Pragma("unroll") for (int nj = 0; nj < 2; ++nj)               \
            _Pragma("unroll") for (int kk = 0; kk < 2; ++kk)           \
        acc[(MH)*4 + mi][(NH)*2 + nj] =                                \
        __builtin_amdgcn_mfma_f32_16x16x32_bf16(                       \
            areg[mi][kk], BR[nj][kk], acc[(MH)*4 + mi][(NH)*2 + nj],   \
            0, 0, 0);                                                  \
    __builtin_amdgcn_s_setprio(0);                                     \
  } while (0)
#define LGKM0                                          \
  asm volatile("s_waitcnt lgkmcnt(0)" ::: "memory");   \
  __builtin_amdgcn_sched_barrier(0)

  // prologue: tile0 fully + tile1 {B0, A0}; leave 2 halves (4 loads) in flight
  STAGE(0, 0, 0, Ab, m0, 0);
  STAGE(0, 0, 1, Ab, m0, 0);
  STAGE(0, 1, 0, Bb, n0, 0);
  STAGE(0, 1, 1, Bb, n0, 0);
  STAGE(1, 1, 0, Bb, n0, 64);
  STAGE(1, 0, 0, Ab, m0, 64);
  asm volatile("s_waitcnt vmcnt(4)" ::: "memory");
  __builtin_amdgcn_s_barrier();

  for (int tt = 0; tt < NT; ++tt) {
    const int rd = tt & 1;
    // ---- phase 1: quadrant (m0,n0) ----
    LOAD_A(0);
    LOAD_B(0, b0r);
    if (tt + 1 < NT) STAGE((tt + 1) & 1, 1, 1, Bb, n0, (tt + 1) * 64);
    __builtin_amdgcn_s_barrier();
    LGKM0;
    MFMA_Q(0, 0, b0r);
    __builtin_amdgcn_s_barrier();
    // ---- phase 2: quadrant (m0,n1) ----
    LOAD_B(1, b1r);
    if (tt + 1 < NT) STAGE((tt + 1) & 1, 0, 1, Ab, m0, (tt + 1) * 64);
    __builtin_amdgcn_s_barrier();
    LGKM0;
    MFMA_Q(0, 1, b1r);
    __builtin_amdgcn_s_barrier();
    // ---- phase 3: quadrant (m1,n1) ----
    LOAD_A(1);
    if (tt + 2 < NT) STAGE(rd, 1, 0, Bb, n0, (tt + 2) * 64);
    __builtin_amdgcn_s_barrier();
    LGKM0;
    MFMA_Q(1, 1, b1r);
    __builtin_amdgcn_s_barrier();
    // ---- phase 4: quadrant (m1,n0) ----
    if (tt + 2 < NT) STAGE(rd, 0, 0, Ab, m0, (tt + 2) * 64);
    __builtin_amdgcn_s_barrier();
    LGKM0;
    MFMA_Q(1, 0, b0r);
    asm volatile("s_waitcnt vmcnt(4)" ::: "memory");
    __builtin_amdgcn_s_barrier();
  }

  // epilogue
  const ET* Eb = E + (size_t)b * strideE;
  CT* Cb = C + (size_t)b * strideC;
#pragma unroll
  for (int mi = 0; mi < 8; ++mi) {
#pragma unroll
    for (int r = 0; r < 4; ++r) {
      const int row = m0 + wm + mi * 16 + (lane >> 4) * 4 + r;
#pragma unroll
      for (int nj = 0; nj < 4; ++nj) {
        const int col = n0 + wn + nj * 16 + (lane & 15);
        float v = c0 * acc[mi][nj][r];
        if (HASE) v += c1 * ldE(Eb + (size_t)row * 1024 + col);
        stC(Cb + (size_t)row * 1024 + col, v);
      }
    }
  }
#undef LOAD_A
#undef LOAD_B
#undef MFMA_Q
#undef LGKM0
}

// ---------------------------------------------------------------------------
// out = support·(theta*W + (1-theta)*I), support = 0.9*(adj·X_b) + 0.1*h0
// theta = log(1.5) (static: lamda=0.5, l=1 in setup_inputs)
// ---------------------------------------------------------------------------
extern "C" void kernel_launch(void* const* d_in, const int* in_sizes, int n_in,
                              void* d_out, int out_size, void* d_ws,
                              size_t ws_size, hipStream_t stream) {
  const float* X = (const float*)d_in[0];    // [16,1024,1024] f32
  const float* adj = (const float*)d_in[1];  // [1024,1024] f32
  const float* h0 = (const float*)d_in[2];   // [16,1024,1024] f32
  const float* W = (const float*)d_in[3];    // [1024,1024] f32
  float* out = (float*)d_out;                // [16,1024,1024] f32

  const size_t NF = 1024ull * 1024ull;
  unsigned short* XT = (unsigned short*)d_ws;  // 16*NF bf16
  unsigned short* WT = XT + 16 * NF;           // NF bf16 (theta*W^T+(1-theta)I)
  unsigned short* AJ = WT + NF;                // NF bf16
  unsigned short* S = AJ + NF;                 // 16*NF bf16

  const float theta = 0.405465108f;  // log(1.5)
  const float alpha = 0.1f;

  conv_transpose64<<<dim3(16, 16, 16), 256, 0, stream>>>(X, XT, 1024, 1024);
  conv_transpose_wprime<<<dim3(16, 16, 1), 256, 0, stream>>>(
      W, WT, theta, 1.0f - theta);
  conv_bf16<<<dim3(1024), 256, 0, stream>>>(adj, AJ, 1024 * 1024);

  // S = bf16( 0.9*(adj · X_b) + 0.1*h0 )
  gemm256<float, unsigned short, true>
      <<<dim3(4, 4, 16), 512, 0, stream>>>(AJ, 0, XT, NF, h0, NF, S, NF,
                                           1.0f - alpha, alpha);
  // out = f32( S · W'^T )
  gemm256<unsigned short, float, false>
      <<<dim3(4, 4, 16), 512, 0, stream>>>(S, NF, WT, 0, S, NF, out, NF,
                                           1.0f, 0.0f);
}